// Round 1
// baseline (20.811 us; speedup 1.0000x reference)
//
#include <hip/hip_runtime.h>
#include <math.h>

#define NTAB 4096            // table intervals; table has NTAB+1 entries
#define TLIM 16.0f           // t range [-TLIM, TLIM]

// ---------------------------------------------------------------------------
// Kernel 1: build LUT p(t) for t in [-16,16], NTAB+1 entries.
// One wave (64 lanes) per table entry. Lane j owns hidden2 row j (64 rows).
// e1_w (64x128) is staged transposed into LDS: wt[k*65 + j] = e1_w[j*128+k]
// (stride 65 -> conflict-free reads and writes).
// ---------------------------------------------------------------------------
__global__ __launch_bounds__(256) void build_tab_kernel(
    const float* __restrict__ e0w, const float* __restrict__ e0b,
    const float* __restrict__ e1w, const float* __restrict__ e1b,
    const float* __restrict__ e2w, const float* __restrict__ e2b,
    const float* __restrict__ fmw, const float* __restrict__ fmb,
    const float* __restrict__ c1w, const float* __restrict__ c1b,
    const float* __restrict__ p1w, const float* __restrict__ p1b,
    const float* __restrict__ c2w, const float* __restrict__ c2b,
    const float* __restrict__ p2w, const float* __restrict__ p2b,
    const float* __restrict__ c3w, const float* __restrict__ c3b,
    const float* __restrict__ hw,  const float* __restrict__ hb,
    float* __restrict__ tab)
{
    __shared__ float wt[128 * 65];
    const int tid = threadIdx.x;

    // Stage e1_w transposed: coalesced global reads, conflict-free LDS writes.
    #pragma unroll
    for (int i = 0; i < 32; ++i) {
        int idx = i * 256 + tid;          // 0..8191
        int j = idx >> 7;                 // row   (0..63)
        int k = idx & 127;                // col   (0..127)
        wt[k * 65 + j] = e1w[idx];
    }
    __syncthreads();

    const int wave = tid >> 6;
    const int lane = tid & 63;
    const int e = blockIdx.x * 4 + wave;  // table entry index
    if (e > NTAB) return;

    const float t = -TLIM + (2.0f * TLIM) * (float)e / (float)NTAB;
    const float s = 1.0f / (1.0f + __expf(-t) * 0.0f + expf(-t)); // plain expf
    // (the expression above is just expf; keep it simple)
    const float sv = 1.0f / (1.0f + expf(-t));

    // h2[lane] = relu( sum_k e1_w[lane,k] * relu(e0_w[k]*s + e0_b[k]) + e1_b[lane] )
    float acc = e1b[lane];
    #pragma unroll 4
    for (int k = 0; k < 128; ++k) {
        float h1 = fmaxf(fmaf(e0w[k], sv, e0b[k]), 0.0f);
        acc = fmaf(wt[k * 65 + lane], h1, acc);
    }
    float h2 = fmaxf(acc, 0.0f);

    // latent = e2_w (2x64) @ h2 + e2_b : wave-wide butterfly reduction
    float v0 = e2w[lane] * h2;
    float v1 = e2w[64 + lane] * h2;
    #pragma unroll
    for (int off = 32; off > 0; off >>= 1) {
        v0 += __shfl_xor(v0, off);
        v1 += __shfl_xor(v1, off);
    }
    float l0 = v0 + e2b[0];
    float l1 = v1 + e2b[1];

    // QCNN tanh chain (tiny; computed redundantly in every lane)
    float y0[4], y1[4], y2[3], y3[2];
    #pragma unroll
    for (int o = 0; o < 4; ++o)
        y0[o] = tanhf(fmaf(fmw[o*2], l0, fmaf(fmw[o*2+1], l1, fmb[o])));
    #pragma unroll
    for (int o = 0; o < 4; ++o)
        y1[o] = tanhf(fmaf(c1w[o*4], y0[0], fmaf(c1w[o*4+1], y0[1],
                      fmaf(c1w[o*4+2], y0[2], fmaf(c1w[o*4+3], y0[3], c1b[o])))));
    #pragma unroll
    for (int o = 0; o < 3; ++o)
        y2[o] = tanhf(fmaf(p1w[o*4], y1[0], fmaf(p1w[o*4+1], y1[1],
                      fmaf(p1w[o*4+2], y1[2], fmaf(p1w[o*4+3], y1[3], p1b[o])))));
    #pragma unroll
    for (int o = 0; o < 2; ++o)
        y3[o] = tanhf(fmaf(c2w[o*3], y2[0], fmaf(c2w[o*3+1], y2[1],
                      fmaf(c2w[o*3+2], y2[2], c2b[o]))));
    float y4 = tanhf(fmaf(p2w[0], y3[0], fmaf(p2w[1], y3[1], p2b[0])));
    float y5 = tanhf(fmaf(c3w[0], y4, c3b[0]));
    float g0 = fmaf(hw[0], y5, hb[0]);
    float g1 = fmaf(hw[1], y5, hb[1]);

    // softmax over 2 logits -> p0 = sigmoid(g0 - g1)
    float p0 = 1.0f / (1.0f + expf(g1 - g0));

    if (lane == 0) tab[e] = p0;
    (void)s;
}

// ---------------------------------------------------------------------------
// Kernel 2: memory-bound eval. 2 samples per thread.
//   t = dot(x, conv_w) + conv_b ; clamp ; lerp table ; write (p, 1-p)
// ---------------------------------------------------------------------------
__global__ __launch_bounds__(256) void eval_kernel(
    const float4* __restrict__ x4,
    const float*  __restrict__ convw,
    const float*  __restrict__ convb,
    const float*  __restrict__ tab,
    float4* __restrict__ out4,
    int npairs)
{
    const float w0 = convw[0], w1 = convw[1], w2 = convw[2], w3 = convw[3];
    const float cb = convb[0];
    const float scale = (float)NTAB / (2.0f * TLIM);   // 128.0f

    int i = blockIdx.x * blockDim.x + threadIdx.x;
    if (i >= npairs) return;

    float4 xa = x4[2 * i];
    float4 xb = x4[2 * i + 1];

    float ta = fmaf(xa.x, w0, fmaf(xa.y, w1, fmaf(xa.z, w2, fmaf(xa.w, w3, cb))));
    float tb = fmaf(xb.x, w0, fmaf(xb.y, w1, fmaf(xb.z, w2, fmaf(xb.w, w3, cb))));

    float fa = fminf(fmaxf((ta + TLIM) * scale, 0.0f), (float)NTAB - 0.001f);
    float fb = fminf(fmaxf((tb + TLIM) * scale, 0.0f), (float)NTAB - 0.001f);

    int ia = (int)fa; float ra = fa - (float)ia;
    int ib = (int)fb; float rb = fb - (float)ib;

    float a0 = tab[ia], a1 = tab[ia + 1];
    float b0 = tab[ib], b1 = tab[ib + 1];

    float pa = fmaf(ra, a1 - a0, a0);
    float pb = fmaf(rb, b1 - b0, b0);

    out4[i] = make_float4(pa, 1.0f - pa, pb, 1.0f - pb);
}

extern "C" void kernel_launch(void* const* d_in, const int* in_sizes, int n_in,
                              void* d_out, int out_size, void* d_ws, size_t ws_size,
                              hipStream_t stream) {
    const float* x     = (const float*)d_in[0];
    const float* convw = (const float*)d_in[1];
    const float* convb = (const float*)d_in[2];
    const float* e0w   = (const float*)d_in[3];
    const float* e0b   = (const float*)d_in[4];
    const float* e1w   = (const float*)d_in[5];
    const float* e1b   = (const float*)d_in[6];
    const float* e2w   = (const float*)d_in[7];
    const float* e2b   = (const float*)d_in[8];
    const float* fmw   = (const float*)d_in[9];
    const float* fmb   = (const float*)d_in[10];
    const float* c1w   = (const float*)d_in[11];
    const float* c1b   = (const float*)d_in[12];
    const float* p1w   = (const float*)d_in[13];
    const float* p1b   = (const float*)d_in[14];
    const float* c2w   = (const float*)d_in[15];
    const float* c2b   = (const float*)d_in[16];
    const float* p2w   = (const float*)d_in[17];
    const float* p2b   = (const float*)d_in[18];
    const float* c3w   = (const float*)d_in[19];
    const float* c3b   = (const float*)d_in[20];
    const float* hw    = (const float*)d_in[21];
    const float* hb    = (const float*)d_in[22];

    float* tab = (float*)d_ws;                 // (NTAB+1) floats = 16388 B

    const int B = in_sizes[0] / 4;             // 1048576 samples
    const int npairs = B / 2;

    // Build LUT: one wave per entry, 4 entries per 256-thread block.
    int nblocks_tab = (NTAB + 1 + 3) / 4;      // 1025
    build_tab_kernel<<<nblocks_tab, 256, 0, stream>>>(
        e0w, e0b, e1w, e1b, e2w, e2b, fmw, fmb, c1w, c1b,
        p1w, p1b, c2w, c2b, p2w, p2b, c3w, c3b, hw, hb, tab);

    // Evaluate all samples.
    int nblocks = (npairs + 255) / 256;        // 2048
    eval_kernel<<<nblocks, 256, 0, stream>>>(
        (const float4*)x, convw, convb, tab, (float4*)d_out, npairs);
}

// Round 2
// 17.614 us; speedup vs baseline: 1.1815x; 1.1815x over previous
//
#include <hip/hip_runtime.h>
#include <math.h>

#define NTAB 1024            // table intervals; table has NTAB+1 entries
#define TLIM 8.0f            // t range [-TLIM, TLIM]

// ---------------------------------------------------------------------------
// Kernel 1: build LUT p(t) for t in [-TLIM,TLIM], NTAB+1 entries.
// One wave (64 lanes) per table entry. Lane j owns hidden2 row j (64 rows).
// e1_w (64x128) is staged transposed into LDS: wt[k*65 + j] = e1_w[j*128+k]
// (stride 65 -> conflict-free reads and writes).
// ---------------------------------------------------------------------------
__global__ __launch_bounds__(256) void build_tab_kernel(
    const float* __restrict__ e0w, const float* __restrict__ e0b,
    const float* __restrict__ e1w, const float* __restrict__ e1b,
    const float* __restrict__ e2w, const float* __restrict__ e2b,
    const float* __restrict__ fmw, const float* __restrict__ fmb,
    const float* __restrict__ c1w, const float* __restrict__ c1b,
    const float* __restrict__ p1w, const float* __restrict__ p1b,
    const float* __restrict__ c2w, const float* __restrict__ c2b,
    const float* __restrict__ p2w, const float* __restrict__ p2b,
    const float* __restrict__ c3w, const float* __restrict__ c3b,
    const float* __restrict__ hw,  const float* __restrict__ hb,
    float* __restrict__ tab)
{
    __shared__ float wt[128 * 65];
    const int tid = threadIdx.x;

    // Stage e1_w transposed: coalesced global reads, conflict-free LDS writes.
    #pragma unroll
    for (int i = 0; i < 32; ++i) {
        int idx = i * 256 + tid;          // 0..8191
        int j = idx >> 7;                 // row   (0..63)
        int k = idx & 127;                // col   (0..127)
        wt[k * 65 + j] = e1w[idx];
    }
    __syncthreads();

    const int wave = tid >> 6;
    const int lane = tid & 63;
    const int e = blockIdx.x * 4 + wave;  // table entry index
    if (e > NTAB) return;

    const float t = -TLIM + (2.0f * TLIM) * (float)e / (float)NTAB;
    const float sv = 1.0f / (1.0f + expf(-t));

    // h2[lane] = relu( sum_k e1_w[lane,k] * relu(e0_w[k]*sv + e0_b[k]) + e1_b[lane] )
    float acc = e1b[lane];
    #pragma unroll 8
    for (int k = 0; k < 128; ++k) {
        float h1 = fmaxf(fmaf(e0w[k], sv, e0b[k]), 0.0f);
        acc = fmaf(wt[k * 65 + lane], h1, acc);
    }
    float h2 = fmaxf(acc, 0.0f);

    // latent = e2_w (2x64) @ h2 + e2_b : wave-wide butterfly reduction
    float v0 = e2w[lane] * h2;
    float v1 = e2w[64 + lane] * h2;
    #pragma unroll
    for (int off = 32; off > 0; off >>= 1) {
        v0 += __shfl_xor(v0, off);
        v1 += __shfl_xor(v1, off);
    }
    float l0 = v0 + e2b[0];
    float l1 = v1 + e2b[1];

    // QCNN tanh chain (tiny; computed redundantly in every lane)
    float y0[4], y1[4], y2[3], y3[2];
    #pragma unroll
    for (int o = 0; o < 4; ++o)
        y0[o] = tanhf(fmaf(fmw[o*2], l0, fmaf(fmw[o*2+1], l1, fmb[o])));
    #pragma unroll
    for (int o = 0; o < 4; ++o)
        y1[o] = tanhf(fmaf(c1w[o*4], y0[0], fmaf(c1w[o*4+1], y0[1],
                      fmaf(c1w[o*4+2], y0[2], fmaf(c1w[o*4+3], y0[3], c1b[o])))));
    #pragma unroll
    for (int o = 0; o < 3; ++o)
        y2[o] = tanhf(fmaf(p1w[o*4], y1[0], fmaf(p1w[o*4+1], y1[1],
                      fmaf(p1w[o*4+2], y1[2], fmaf(p1w[o*4+3], y1[3], p1b[o])))));
    #pragma unroll
    for (int o = 0; o < 2; ++o)
        y3[o] = tanhf(fmaf(c2w[o*3], y2[0], fmaf(c2w[o*3+1], y2[1],
                      fmaf(c2w[o*3+2], y2[2], c2b[o]))));
    float y4 = tanhf(fmaf(p2w[0], y3[0], fmaf(p2w[1], y3[1], p2b[0])));
    float y5 = tanhf(fmaf(c3w[0], y4, c3b[0]));
    float g0 = fmaf(hw[0], y5, hb[0]);
    float g1 = fmaf(hw[1], y5, hb[1]);

    // softmax over 2 logits -> p0 = sigmoid(g0 - g1)
    float p0 = 1.0f / (1.0f + expf(g1 - g0));

    if (lane == 0) tab[e] = p0;
}

// ---------------------------------------------------------------------------
// Kernel 2: memory-bound eval, 4 samples per thread.
// Table staged in LDS (4.1 KB) so the random lerp gathers are ds_read_b32
// (bank conflicts ~2-4-way: near-free) instead of serialized L1 line fan-out.
// ---------------------------------------------------------------------------
__global__ __launch_bounds__(256) void eval_kernel(
    const float4* __restrict__ x4,
    const float*  __restrict__ convw,
    const float*  __restrict__ convb,
    const float*  __restrict__ tab,
    float4* __restrict__ out4,
    int nthreads)
{
    __shared__ float ltab[NTAB + 1];
    const int tid = threadIdx.x;

    // Stage table: 1025 floats, 256 threads -> 4-5 each, coalesced.
    #pragma unroll
    for (int i = tid; i < NTAB + 1; i += 256)
        ltab[i] = tab[i];
    __syncthreads();

    const float w0 = convw[0], w1 = convw[1], w2 = convw[2], w3 = convw[3];
    const float cb = convb[0];
    const float scale = (float)NTAB / (2.0f * TLIM);   // 64.0f

    int i = blockIdx.x * blockDim.x + tid;
    if (i >= nthreads) return;

    float4 xs[4];
    #pragma unroll
    for (int s = 0; s < 4; ++s) xs[s] = x4[4 * i + s];

    float p[4];
    #pragma unroll
    for (int s = 0; s < 4; ++s) {
        float t = fmaf(xs[s].x, w0, fmaf(xs[s].y, w1,
                  fmaf(xs[s].z, w2, fmaf(xs[s].w, w3, cb))));
        float f = fminf(fmaxf((t + TLIM) * scale, 0.0f), (float)NTAB - 0.001f);
        int   k = (int)f;
        float r = f - (float)k;
        float a0 = ltab[k], a1 = ltab[k + 1];
        p[s] = fmaf(r, a1 - a0, a0);
    }

    out4[2 * i]     = make_float4(p[0], 1.0f - p[0], p[1], 1.0f - p[1]);
    out4[2 * i + 1] = make_float4(p[2], 1.0f - p[2], p[3], 1.0f - p[3]);
}

extern "C" void kernel_launch(void* const* d_in, const int* in_sizes, int n_in,
                              void* d_out, int out_size, void* d_ws, size_t ws_size,
                              hipStream_t stream) {
    const float* x     = (const float*)d_in[0];
    const float* convw = (const float*)d_in[1];
    const float* convb = (const float*)d_in[2];
    const float* e0w   = (const float*)d_in[3];
    const float* e0b   = (const float*)d_in[4];
    const float* e1w   = (const float*)d_in[5];
    const float* e1b   = (const float*)d_in[6];
    const float* e2w   = (const float*)d_in[7];
    const float* e2b   = (const float*)d_in[8];
    const float* fmw   = (const float*)d_in[9];
    const float* fmb   = (const float*)d_in[10];
    const float* c1w   = (const float*)d_in[11];
    const float* c1b   = (const float*)d_in[12];
    const float* p1w   = (const float*)d_in[13];
    const float* p1b   = (const float*)d_in[14];
    const float* c2w   = (const float*)d_in[15];
    const float* c2b   = (const float*)d_in[16];
    const float* p2w   = (const float*)d_in[17];
    const float* p2b   = (const float*)d_in[18];
    const float* c3w   = (const float*)d_in[19];
    const float* c3b   = (const float*)d_in[20];
    const float* hw    = (const float*)d_in[21];
    const float* hb    = (const float*)d_in[22];

    float* tab = (float*)d_ws;                 // (NTAB+1) floats = 4.1 KB

    const int B = in_sizes[0] / 4;             // 1048576 samples

    // Build LUT: one wave per entry, 4 entries per 256-thread block.
    int nblocks_tab = (NTAB + 1 + 3) / 4;      // 257
    build_tab_kernel<<<nblocks_tab, 256, 0, stream>>>(
        e0w, e0b, e1w, e1b, e2w, e2b, fmw, fmb, c1w, c1b,
        p1w, p1b, c2w, c2b, p2w, p2b, c3w, c3b, hw, hb, tab);

    // Evaluate: 4 samples per thread.
    int nthreads = B / 4;                      // 262144
    int nblocks = (nthreads + 255) / 256;      // 1024
    eval_kernel<<<nblocks, 256, 0, stream>>>(
        (const float4*)x, convw, convb, tab, (float4*)d_out, nthreads);
}

// Round 3
// 16.466 us; speedup vs baseline: 1.2638x; 1.0697x over previous
//
#include <hip/hip_runtime.h>
#include <math.h>

#define NTAB 512             // table intervals; table has NTAB+1 entries
#define TLIM 8.0f            // t range [-TLIM, TLIM]

// ---------------------------------------------------------------------------
// Kernel 1: build LUT p(t) for t in [-TLIM,TLIM], NTAB+1 entries.
// One wave (64 lanes) per table entry. Lane j owns hidden2 row j (64 rows).
// e1_w (64x128) staged transposed in LDS (stride 65 -> conflict-free).
// ---------------------------------------------------------------------------
__global__ __launch_bounds__(256) void build_tab_kernel(
    const float* __restrict__ e0w, const float* __restrict__ e0b,
    const float* __restrict__ e1w, const float* __restrict__ e1b,
    const float* __restrict__ e2w, const float* __restrict__ e2b,
    const float* __restrict__ fmw, const float* __restrict__ fmb,
    const float* __restrict__ c1w, const float* __restrict__ c1b,
    const float* __restrict__ p1w, const float* __restrict__ p1b,
    const float* __restrict__ c2w, const float* __restrict__ c2b,
    const float* __restrict__ p2w, const float* __restrict__ p2b,
    const float* __restrict__ c3w, const float* __restrict__ c3b,
    const float* __restrict__ hw,  const float* __restrict__ hb,
    float* __restrict__ tab)
{
    __shared__ float wt[128 * 65];
    const int tid = threadIdx.x;

    #pragma unroll
    for (int i = 0; i < 32; ++i) {
        int idx = i * 256 + tid;          // 0..8191
        int j = idx >> 7;                 // row   (0..63)
        int k = idx & 127;                // col   (0..127)
        wt[k * 65 + j] = e1w[idx];
    }
    __syncthreads();

    const int wave = tid >> 6;
    const int lane = tid & 63;
    const int e = blockIdx.x * 4 + wave;  // table entry index
    if (e > NTAB) return;

    const float t = -TLIM + (2.0f * TLIM) * (float)e / (float)NTAB;
    const float sv = 1.0f / (1.0f + expf(-t));

    // h2[lane] = relu( sum_k e1_w[lane,k] * relu(e0_w[k]*sv + e0_b[k]) + e1_b[lane] )
    // 4 accumulators to cut the serial FMA dependency chain 128 -> 32.
    float a0 = e1b[lane], a1 = 0.0f, a2 = 0.0f, a3 = 0.0f;
    #pragma unroll 4
    for (int k = 0; k < 128; k += 4) {
        float h10 = fmaxf(fmaf(e0w[k + 0], sv, e0b[k + 0]), 0.0f);
        float h11 = fmaxf(fmaf(e0w[k + 1], sv, e0b[k + 1]), 0.0f);
        float h12 = fmaxf(fmaf(e0w[k + 2], sv, e0b[k + 2]), 0.0f);
        float h13 = fmaxf(fmaf(e0w[k + 3], sv, e0b[k + 3]), 0.0f);
        a0 = fmaf(wt[(k + 0) * 65 + lane], h10, a0);
        a1 = fmaf(wt[(k + 1) * 65 + lane], h11, a1);
        a2 = fmaf(wt[(k + 2) * 65 + lane], h12, a2);
        a3 = fmaf(wt[(k + 3) * 65 + lane], h13, a3);
    }
    float h2 = fmaxf((a0 + a1) + (a2 + a3), 0.0f);

    // latent = e2_w (2x64) @ h2 + e2_b : wave-wide butterfly reduction
    float v0 = e2w[lane] * h2;
    float v1 = e2w[64 + lane] * h2;
    #pragma unroll
    for (int off = 32; off > 0; off >>= 1) {
        v0 += __shfl_xor(v0, off);
        v1 += __shfl_xor(v1, off);
    }
    float l0 = v0 + e2b[0];
    float l1 = v1 + e2b[1];

    // QCNN tanh chain (tiny; computed redundantly in every lane)
    float y0[4], y1[4], y2[3], y3[2];
    #pragma unroll
    for (int o = 0; o < 4; ++o)
        y0[o] = tanhf(fmaf(fmw[o*2], l0, fmaf(fmw[o*2+1], l1, fmb[o])));
    #pragma unroll
    for (int o = 0; o < 4; ++o)
        y1[o] = tanhf(fmaf(c1w[o*4], y0[0], fmaf(c1w[o*4+1], y0[1],
                      fmaf(c1w[o*4+2], y0[2], fmaf(c1w[o*4+3], y0[3], c1b[o])))));
    #pragma unroll
    for (int o = 0; o < 3; ++o)
        y2[o] = tanhf(fmaf(p1w[o*4], y1[0], fmaf(p1w[o*4+1], y1[1],
                      fmaf(p1w[o*4+2], y1[2], fmaf(p1w[o*4+3], y1[3], p1b[o])))));
    #pragma unroll
    for (int o = 0; o < 2; ++o)
        y3[o] = tanhf(fmaf(c2w[o*3], y2[0], fmaf(c2w[o*3+1], y2[1],
                      fmaf(c2w[o*3+2], y2[2], c2b[o]))));
    float y4 = tanhf(fmaf(p2w[0], y3[0], fmaf(p2w[1], y3[1], p2b[0])));
    float y5 = tanhf(fmaf(c3w[0], y4, c3b[0]));
    float g0 = fmaf(hw[0], y5, hb[0]);
    float g1 = fmaf(hw[1], y5, hb[1]);

    // softmax over 2 logits -> p0 = sigmoid(g0 - g1)
    float p0 = 1.0f / (1.0f + expf(g1 - g0));

    if (lane == 0) tab[e] = p0;
}

// ---------------------------------------------------------------------------
// Kernel 2: memory-bound eval, 4 samples per thread, block-tiled so every
// global load/store instruction is lane-dense (16B/lane loads, 8B/lane
// stores). Table staged in LDS as (value, delta) float2 -> one ds_read_b64
// per sample.
// ---------------------------------------------------------------------------
__global__ __launch_bounds__(256) void eval_kernel(
    const float4* __restrict__ x4,
    const float*  __restrict__ convw,
    const float*  __restrict__ convb,
    const float*  __restrict__ tab,
    float2* __restrict__ out2)
{
    __shared__ float2 ltab[NTAB + 1];
    const int tid = threadIdx.x;
    const int base = blockIdx.x * 1024;   // 1024 samples per block

    // Issue x loads first so they are in flight during table staging.
    float4 xs[4];
    #pragma unroll
    for (int j = 0; j < 4; ++j)
        xs[j] = x4[base + j * 256 + tid];

    // Stage table as (value, delta): 513 entries, 256 threads.
    for (int i = tid; i < NTAB + 1; i += 256) {
        float v  = tab[i];
        float vn = (i < NTAB) ? tab[i + 1] : v;
        ltab[i] = make_float2(v, vn - v);
    }
    __syncthreads();

    const float w0 = convw[0], w1 = convw[1], w2 = convw[2], w3 = convw[3];
    const float cb = convb[0];
    const float scale = (float)NTAB / (2.0f * TLIM);   // 32.0f

    #pragma unroll
    for (int j = 0; j < 4; ++j) {
        float t = fmaf(xs[j].x, w0, fmaf(xs[j].y, w1,
                  fmaf(xs[j].z, w2, fmaf(xs[j].w, w3, cb))));
        float f = fminf(fmaxf((t + TLIM) * scale, 0.0f), (float)NTAB - 0.001f);
        int   k = (int)f;
        float r = f - (float)k;
        float2 vd = ltab[k];
        float p = fmaf(r, vd.y, vd.x);
        out2[base + j * 256 + tid] = make_float2(p, 1.0f - p);
    }
}

extern "C" void kernel_launch(void* const* d_in, const int* in_sizes, int n_in,
                              void* d_out, int out_size, void* d_ws, size_t ws_size,
                              hipStream_t stream) {
    const float* x     = (const float*)d_in[0];
    const float* convw = (const float*)d_in[1];
    const float* convb = (const float*)d_in[2];
    const float* e0w   = (const float*)d_in[3];
    const float* e0b   = (const float*)d_in[4];
    const float* e1w   = (const float*)d_in[5];
    const float* e1b   = (const float*)d_in[6];
    const float* e2w   = (const float*)d_in[7];
    const float* e2b   = (const float*)d_in[8];
    const float* fmw   = (const float*)d_in[9];
    const float* fmb   = (const float*)d_in[10];
    const float* c1w   = (const float*)d_in[11];
    const float* c1b   = (const float*)d_in[12];
    const float* p1w   = (const float*)d_in[13];
    const float* p1b   = (const float*)d_in[14];
    const float* c2w   = (const float*)d_in[15];
    const float* c2b   = (const float*)d_in[16];
    const float* p2w   = (const float*)d_in[17];
    const float* p2b   = (const float*)d_in[18];
    const float* c3w   = (const float*)d_in[19];
    const float* c3b   = (const float*)d_in[20];
    const float* hw    = (const float*)d_in[21];
    const float* hb    = (const float*)d_in[22];

    float* tab = (float*)d_ws;                 // (NTAB+1) floats

    const int B = in_sizes[0] / 4;             // 1048576 samples

    // Build LUT: one wave per entry, 4 entries per 256-thread block.
    int nblocks_tab = (NTAB + 1 + 3) / 4;      // 129
    build_tab_kernel<<<nblocks_tab, 256, 0, stream>>>(
        e0w, e0b, e1w, e1b, e2w, e2b, fmw, fmb, c1w, c1b,
        p1w, p1b, c2w, c2b, p2w, p2b, c3w, c3b, hw, hb, tab);

    // Evaluate: 1024 samples per block.
    int nblocks = B / 1024;                    // 1024
    eval_kernel<<<nblocks, 256, 0, stream>>>(
        (const float4*)x, convw, convb, tab, (float2*)d_out);
}